// Round 5
// baseline (1354.500 us; speedup 1.0000x reference)
//
#include <hip/hip_runtime.h>
#include <cstdint>

// FP8(e4m3 bit-pulse) -> FP16 bit-pulse converter, wave-cooperative,
// fully-coalesced loads AND stores.
// Per iteration each 64-lane wave handles 64 groups (2 KiB in, 4 KiB out):
//   load0: lane l <- in4[2*base + l]        (1 KiB contiguous)
//   load1: lane l <- in4[2*base + 64 + l]   (1 KiB contiguous)
//   lane packs each half-group (4 floats) into a nibble; shfl_xor(1) merges
//   the pair -> every lane holds full bytes of groups base+(l>>1) and
//   base+32+(l>>1); lane decodes ONE group (even lanes low, odd lanes high);
//   4 stores, each 1 KiB contiguous, words routed by ds_bpermute shuffles.

typedef float f32x4 __attribute__((ext_vector_type(4)));

__global__ __launch_bounds__(256) void fp8_to_fp16_bits_kernel(
    const f32x4* __restrict__ in4,   // 2 per group
    f32x4* __restrict__ out4,        // 4 per group
    int n_groups)                    // multiple of 64 (2^24 here)
{
    const int lane   = threadIdx.x & 63;
    const int gwave  = (int)((blockIdx.x * blockDim.x + threadIdx.x) >> 6);
    const int nwaves = (int)((gridDim.x * blockDim.x) >> 6);

    const int q    = lane & 3;        // which quad of 16 bits this lane stores
    const int sh3  = 12 - 4 * q;      // LSB position of that quad
    const int s2   = 2 * (lane >> 2); // shuffle source base for stores
    const int nibsh = (lane & 1) ? 0 : 4;  // even lane = high nibble of byte

    for (int base = gwave * 64; base < n_groups; base += nwaves * 64) {
        const f32x4* ip = in4 + 2 * base;
        f32x4 r0 = ip[lane];          // half (lane&1) of group base+(lane>>1)
        f32x4 r1 = ip[64 + lane];     // half (lane&1) of group base+32+(lane>>1)

        // pack each f32x4 half-group into a 4-bit nibble (MSB-first within half)
        uint32_t c0 = (((r0[0] != 0.0f) << 3) | ((r0[1] != 0.0f) << 2) |
                       ((r0[2] != 0.0f) << 1) |  (r0[3] != 0.0f)) << nibsh;
        uint32_t c1 = (((r1[0] != 0.0f) << 3) | ((r1[1] != 0.0f) << 2) |
                       ((r1[2] != 0.0f) << 1) |  (r1[3] != 0.0f)) << nibsh;
        uint32_t pk   = c0 | (c1 << 8);
        uint32_t comb = pk | (uint32_t)__shfl_xor((int)pk, 1, 64);
        // comb bits 0-7  = byte of group base+(lane>>1)
        // comb bits 8-15 = byte of group base+32+(lane>>1)

        // lane decodes one group: even -> low byte, odd -> high byte
        uint32_t byte = (lane & 1) ? (comb >> 8) & 0xFFu : comb & 0xFFu;

        // byte = {s,e3,e2,e1,e0,m2,m1,m0} MSB-first
        uint32_t s = byte >> 7;
        uint32_t e = (byte >> 3) & 0xFu;
        uint32_t m = byte & 7u;
        uint32_t m2 = (m >> 2) & 1u, m1 = (m >> 1) & 1u, m0 = m & 1u;

        uint32_t exp5 = e  ? e + 8u
                      : m2 ? 8u
                      : m1 ? 7u
                      : m0 ? 6u
                      :      0u;
        uint32_t mant = e  ? (m << 7)
                      : m2 ? ((m & 3u) << 8)
                      : m1 ? ((m & 1u) << 9)
                      :      0u;
        // bit15 = sign, 14..10 = exp MSB-first, 9..0 = mantissa MSB-first
        uint32_t word = (s << 15) | (exp5 << 10) | mant;

        // lane l holds group g(l) = (l&1)*32 + (l>>1); inverse for group g':
        // g'<32 -> lane 2g', g'>=32 -> lane 2(g'-32)+1.
        // store k writes group 16k+(l>>2): src lanes are s2 / s2+32 / s2+1 / s2+33
        f32x4* op = out4 + 4 * base;
        const int srcs[4] = { s2, s2 + 32, s2 + 1, s2 + 33 };
        #pragma unroll
        for (int k = 0; k < 4; ++k) {
            uint32_t w = (uint32_t)__shfl((int)word, srcs[k], 64);
            f32x4 r;
            r[0] = ((w >> (sh3 + 3)) & 1u) ? 1.0f : 0.0f;
            r[1] = ((w >> (sh3 + 2)) & 1u) ? 1.0f : 0.0f;
            r[2] = ((w >> (sh3 + 1)) & 1u) ? 1.0f : 0.0f;
            r[3] = ((w >> (sh3    )) & 1u) ? 1.0f : 0.0f;
            op[64 * k + lane] = r;
        }
    }
}

extern "C" void kernel_launch(void* const* d_in, const int* in_sizes, int n_in,
                              void* d_out, int out_size, void* d_ws, size_t ws_size,
                              hipStream_t stream)
{
    const f32x4* in4 = (const f32x4*)d_in[0];
    f32x4* out4 = (f32x4*)d_out;
    int n_groups = in_sizes[0] / 8;   // 16,777,216 (multiple of 64)

    // 2048 blocks x 256 threads = 8192 waves; 32 tile-iterations per wave.
    dim3 grid(2048), block(256);
    fp8_to_fp16_bits_kernel<<<grid, block, 0, stream>>>(in4, out4, n_groups);
}